// Round 1
// baseline (449.229 us; speedup 1.0000x reference)
//
#include <hip/hip_runtime.h>
#include <math.h>

namespace {

constexpr int W = 2048, H = 2048, NC = 3, HALF = 1024;
constexpr size_t HWSZ = (size_t)W * H;
constexpr float LAM = 0.05f;

// bicubic constants (exact dyadic rationals)
__device__ __constant__ float c_dummy; // keep namespace non-empty for some compilers

__device__ __forceinline__ int refl(int i, int n) {
    return i < 0 ? -1 - i : (i >= n ? 2 * n - 1 - i : i);
}

// gn[i] = g[i]/sum(g) recovered from normalized 2D kernel diagonal
__global__ void prep_gn(const float* __restrict__ k, float* __restrict__ gn) {
    int t = threadIdx.x;
    if (t < 25) gn[t] = sqrtf(k[t * 25 + t]);
}

// 25-tap wrap conv along rows (W). Each thread -> 4 consecutive outputs.
__global__ __launch_bounds__(256) void conv_h(const float* __restrict__ in,
                                              float* __restrict__ out,
                                              const float* __restrict__ gn) {
    int bid = blockIdx.x;          // NC*H*2
    int seg = bid & 1;
    int row = bid >> 1;            // c*H + i
    int j0 = seg * 1024 + threadIdx.x * 4;
    const float* r = in + (size_t)row * W;
    float g[25];
#pragma unroll
    for (int p = 0; p < 25; ++p) g[p] = gn[p];
    float xv[28];
#pragma unroll
    for (int p = 0; p < 28; ++p) xv[p] = r[(j0 - 12 + p) & (W - 1)];
    float a0 = 0.f, a1 = 0.f, a2 = 0.f, a3 = 0.f;
#pragma unroll
    for (int p = 0; p < 25; ++p) {
        a0 = fmaf(g[p], xv[p], a0);
        a1 = fmaf(g[p], xv[p + 1], a1);
        a2 = fmaf(g[p], xv[p + 2], a2);
        a3 = fmaf(g[p], xv[p + 3], a3);
    }
    *(float4*)(out + (size_t)row * W + j0) = make_float4(a0, a1, a2, a3);
}

// 25-tap wrap conv along cols (H). Each thread -> float4 along W.
__global__ __launch_bounds__(256) void conv_v(const float* __restrict__ in,
                                              float* __restrict__ out,
                                              const float* __restrict__ gn) {
    size_t gt = (size_t)blockIdx.x * 256 + threadIdx.x; // NC*H*(W/4)
    int jv = (int)(gt & (W / 4 - 1));
    int rest = (int)(gt >> 9);
    int i = rest & (H - 1);
    int c = rest >> 11;
    const float* base = in + (size_t)c * HWSZ + (size_t)jv * 4;
    float4 acc = make_float4(0.f, 0.f, 0.f, 0.f);
#pragma unroll
    for (int p = 0; p < 25; ++p) {
        int ii = (i - 12 + p) & (H - 1);
        float4 v = *(const float4*)(base + (size_t)ii * W);
        float g = gn[p];
        acc.x = fmaf(g, v.x, acc.x);
        acc.y = fmaf(g, v.y, acc.y);
        acc.z = fmaf(g, v.z, acc.z);
        acc.w = fmaf(g, v.w, acc.w);
    }
    *(float4*)(out + (size_t)c * HWSZ + (size_t)i * W + (size_t)jv * 4) = acc;
}

// bicubic down x2 (no AA): 4x4 taps, weights {-1/16,9/16,9/16,-1/16}, sym pad 1
__global__ __launch_bounds__(256) void down4(const float* __restrict__ in,
                                             float* __restrict__ out) {
    size_t gt = (size_t)blockIdx.x * 256 + threadIdx.x; // NC*HALF*HALF
    int oj = (int)(gt & (HALF - 1));
    int rest = (int)(gt >> 10);
    int oi = rest & (HALF - 1);
    int c = rest >> 10;
    const float wd[4] = {-0.0625f, 0.5625f, 0.5625f, -0.0625f};
    int ri[4], rj[4];
#pragma unroll
    for (int a = 0; a < 4; ++a) {
        ri[a] = refl(2 * oi - 1 + a, H);
        rj[a] = refl(2 * oj - 1 + a, W);
    }
    const float* base = in + (size_t)c * HWSZ;
    float acc = 0.f;
#pragma unroll
    for (int a = 0; a < 4; ++a) {
        const float* rp = base + (size_t)ri[a] * W;
        float s = 0.f;
#pragma unroll
        for (int b = 0; b < 4; ++b) s = fmaf(wd[b], rp[rj[b]], s);
        acc = fmaf(wd[a], s, acc);
    }
    out[(size_t)c * HALF * HALF + (size_t)oi * HALF + oj] = acc;
}

// bicubic up x2: parity-dependent 4 taps per dim, sym pad 2
__global__ __launch_bounds__(256) void up4(const float* __restrict__ in,
                                           float* __restrict__ out) {
    size_t gt = (size_t)blockIdx.x * 256 + threadIdx.x; // NC*H*W
    int j = (int)(gt & (W - 1));
    int rest = (int)(gt >> 11);
    int i = rest & (H - 1);
    int c = rest >> 11;
    const float WE[4] = {-0.0234375f, 0.2265625f, 0.8671875f, -0.0703125f};
    float wi_[4], wj_[4];
#pragma unroll
    for (int a = 0; a < 4; ++a) {
        wi_[a] = (i & 1) ? WE[3 - a] : WE[a];
        wj_[a] = (j & 1) ? WE[3 - a] : WE[a];
    }
    int bi = (i >> 1) + (i & 1) - 2;
    int bj = (j >> 1) + (j & 1) - 2;
    const float* base = in + (size_t)c * HALF * HALF;
    int rj[4];
#pragma unroll
    for (int b = 0; b < 4; ++b) rj[b] = refl(bj + b, HALF);
    float acc = 0.f;
#pragma unroll
    for (int a = 0; a < 4; ++a) {
        const float* rp = base + (size_t)refl(bi + a, HALF) * HALF;
        float s = 0.f;
#pragma unroll
        for (int b = 0; b < 4; ++b) s = fmaf(wj_[b], rp[rj[b]], s);
        acc = fmaf(wi_[a], s, acc);
    }
    out[(size_t)c * HWSZ + (size_t)i * W + j] = acc;
}

// rows: shiftH ∘ convH_wrap fused -> 26-tap (border j=W-1 uses plain 25-tap)
__global__ __launch_bounds__(256) void rowop(const float* __restrict__ in,
                                             float* __restrict__ out,
                                             const float* __restrict__ gn) {
    int bid = blockIdx.x;
    int seg = bid & 1;
    int row = bid >> 1;
    int j0 = seg * 1024 + threadIdx.x * 4;
    const float* r = in + (size_t)row * W;
    float g[25];
#pragma unroll
    for (int p = 0; p < 25; ++p) g[p] = gn[p];
    float hw[26];
    hw[0] = 0.5f * g[0];
#pragma unroll
    for (int t = 1; t < 25; ++t) hw[t] = 0.5f * (g[t] + g[t - 1]);
    hw[25] = 0.5f * g[24];
    float xv[29];
#pragma unroll
    for (int p = 0; p < 29; ++p) xv[p] = r[(j0 - 12 + p) & (W - 1)];
    float acc[4] = {0.f, 0.f, 0.f, 0.f};
#pragma unroll
    for (int t = 0; t < 26; ++t) {
#pragma unroll
        for (int q = 0; q < 4; ++q) acc[q] = fmaf(hw[t], xv[t + q], acc[q]);
    }
    if (j0 + 3 == W - 1) { // shift clamps at last column: no averaging
        float a = 0.f;
#pragma unroll
        for (int p = 0; p < 25; ++p) a = fmaf(g[p], xv[p + 3], a);
        acc[3] = a;
    }
    *(float4*)(out + (size_t)row * W + j0) = make_float4(acc[0], acc[1], acc[2], acc[3]);
}

// antialiased down x2 along H: 8 taps, sym pad 3. out: (NC, HALF, W)
__global__ __launch_bounds__(256) void downaa_h(const float* __restrict__ in,
                                                float* __restrict__ out) {
    size_t gt = (size_t)blockIdx.x * 256 + threadIdx.x; // NC*HALF*(W/4)
    int jv = (int)(gt & (W / 4 - 1));
    int rest = (int)(gt >> 9);
    int oi = rest & (HALF - 1);
    int c = rest >> 10;
    const float WA[8] = {-0.01171875f, -0.03515625f, 0.11328125f, 0.43359375f,
                         0.43359375f,  0.11328125f,  -0.03515625f, -0.01171875f};
    const float* base = in + (size_t)c * HWSZ + (size_t)jv * 4;
    float4 acc = make_float4(0.f, 0.f, 0.f, 0.f);
#pragma unroll
    for (int t = 0; t < 8; ++t) {
        int ii = refl(2 * oi - 3 + t, H);
        float4 v = *(const float4*)(base + (size_t)ii * W);
        acc.x = fmaf(WA[t], v.x, acc.x);
        acc.y = fmaf(WA[t], v.y, acc.y);
        acc.z = fmaf(WA[t], v.z, acc.z);
        acc.w = fmaf(WA[t], v.w, acc.w);
    }
    *(float4*)(out + (size_t)c * ((size_t)HALF * W) + (size_t)oi * W + (size_t)jv * 4) = acc;
}

// antialiased down x2 along W: in (NC, HALF, W) -> hx (NC, HALF, HALF)
__global__ __launch_bounds__(256) void downaa_w(const float* __restrict__ in,
                                                float* __restrict__ out) {
    size_t gt = (size_t)blockIdx.x * 256 + threadIdx.x; // NC*HALF*HALF
    int oj = (int)(gt & (HALF - 1));
    int rest = (int)(gt >> 10);
    int oi = rest & (HALF - 1);
    int c = rest >> 10;
    const float WA[8] = {-0.01171875f, -0.03515625f, 0.11328125f, 0.43359375f,
                         0.43359375f,  0.11328125f,  -0.03515625f, -0.01171875f};
    const float* r = in + (size_t)c * ((size_t)HALF * W) + (size_t)oi * W;
    float acc = 0.f;
#pragma unroll
    for (int t = 0; t < 8; ++t) acc = fmaf(WA[t], r[refl(2 * oj - 3 + t, W)], acc);
    out[(size_t)c * HALF * HALF + (size_t)oi * HALF + oj] = acc;
}

// cols: (shiftV ∘ convV_wrap) on t3, plus fused  + LAM * up2x2(hx)  -> d_out
__global__ __launch_bounds__(256) void final_k(const float* __restrict__ t3,
                                               const float* __restrict__ hx,
                                               float* __restrict__ out,
                                               const float* __restrict__ gn) {
    int bid = blockIdx.x;          // NC*H*2
    int seg = bid & 1;
    int rest = bid >> 1;           // c*H + i
    int i = rest & (H - 1);
    int c = rest >> 11;
    int j0 = seg * 1024 + threadIdx.x * 4;

    float g[25];
#pragma unroll
    for (int p = 0; p < 25; ++p) g[p] = gn[p];
    float hw[26];
    hw[0] = 0.5f * g[0];
#pragma unroll
    for (int t = 1; t < 25; ++t) hw[t] = 0.5f * (g[t] + g[t - 1]);
    hw[25] = 0.5f * g[24];

    const float* base = t3 + (size_t)c * HWSZ + j0;
    float a0 = 0.f, a1 = 0.f, a2 = 0.f, a3 = 0.f;
    if (i < H - 1) {
#pragma unroll
        for (int t = 0; t < 26; ++t) {
            float4 v = *(const float4*)(base + (size_t)((i - 12 + t) & (H - 1)) * W);
            float h = hw[t];
            a0 = fmaf(h, v.x, a0);
            a1 = fmaf(h, v.y, a1);
            a2 = fmaf(h, v.z, a2);
            a3 = fmaf(h, v.w, a3);
        }
    } else { // last row: shift clamps, plain 25-tap conv
#pragma unroll
        for (int p = 0; p < 25; ++p) {
            float4 v = *(const float4*)(base + (size_t)((i - 12 + p) & (H - 1)) * W);
            float gg = g[p];
            a0 = fmaf(gg, v.x, a0);
            a1 = fmaf(gg, v.y, a1);
            a2 = fmaf(gg, v.z, a2);
            a3 = fmaf(gg, v.w, a3);
        }
    }

    // fused bicubic up x2 of hx at (i, j0..j0+3)
    const float WE[4] = {-0.0234375f, 0.2265625f, 0.8671875f, -0.0703125f};
    float wi_[4];
#pragma unroll
    for (int a = 0; a < 4; ++a) wi_[a] = (i & 1) ? WE[3 - a] : WE[a];
    int bi = (i >> 1) + (i & 1) - 2;
    int rr[4];
#pragma unroll
    for (int a = 0; a < 4; ++a) rr[a] = refl(bi + a, HALF);
    int c0 = (j0 >> 1) - 2;
    int rc[6];
#pragma unroll
    for (int b = 0; b < 6; ++b) rc[b] = refl(c0 + b, HALF);
    const float* hb = hx + (size_t)c * HALF * HALF;
    float u0 = 0.f, u1 = 0.f, u2 = 0.f, u3 = 0.f;
#pragma unroll
    for (int a = 0; a < 4; ++a) {
        const float* hr = hb + (size_t)rr[a] * HALF;
        float v0 = hr[rc[0]], v1 = hr[rc[1]], v2 = hr[rc[2]];
        float v3 = hr[rc[3]], v4 = hr[rc[4]], v5 = hr[rc[5]];
        float s0 = WE[0] * v0 + WE[1] * v1 + WE[2] * v2 + WE[3] * v3; // j0   (even)
        float s1 = WE[3] * v1 + WE[2] * v2 + WE[1] * v3 + WE[0] * v4; // j0+1 (odd)
        float s2 = WE[0] * v1 + WE[1] * v2 + WE[2] * v3 + WE[3] * v4; // j0+2 (even)
        float s3 = WE[3] * v2 + WE[2] * v3 + WE[1] * v4 + WE[0] * v5; // j0+3 (odd)
        float wa = wi_[a];
        u0 = fmaf(wa, s0, u0);
        u1 = fmaf(wa, s1, u1);
        u2 = fmaf(wa, s2, u2);
        u3 = fmaf(wa, s3, u3);
    }

    *(float4*)(out + (size_t)c * HWSZ + (size_t)i * W + j0) =
        make_float4(a0 + LAM * u0, a1 + LAM * u1, a2 + LAM * u2, a3 + LAM * u3);
}

} // namespace

extern "C" void kernel_launch(void* const* d_in, const int* in_sizes, int n_in,
                              void* d_out, int out_size, void* d_ws, size_t ws_size,
                              hipStream_t stream) {
    const float* x = (const float*)d_in[0];   // (1,3,2048,2048) f32
    const float* k = (const float*)d_in[1];   // (25,25) f32
    float* ws = (float*)d_ws;

    const size_t full = (size_t)NC * HWSZ;              // 12,582,912
    const size_t halfrow = (size_t)NC * HALF * W;       // 6,291,456
    const size_t quart = (size_t)NC * HALF * HALF;      // 3,145,728

    float* A = ws;                 // full
    float* B = A + full;           // full
    float* Cb = B + full;          // halfrow (r1, later reused for d1)
    float* D = Cb + halfrow;       // quart (hx)
    float* gn = D + quart;         // 25 floats
    float* out = (float*)d_out;

    hipLaunchKernelGGL(prep_gn, dim3(1), dim3(64), 0, stream, k, gn);

    // Branch B first (uses Cb as intermediate)
    hipLaunchKernelGGL(downaa_h, dim3((unsigned)(NC * HALF * (W / 4) / 256)), dim3(256), 0, stream, x, Cb);
    hipLaunchKernelGGL(downaa_w, dim3((unsigned)(quart / 256)), dim3(256), 0, stream, Cb, D);

    // Branch A
    hipLaunchKernelGGL(conv_h, dim3(NC * H * 2), dim3(256), 0, stream, x, A, gn);
    hipLaunchKernelGGL(conv_v, dim3((unsigned)(full / 4 / 256)), dim3(256), 0, stream, A, B, gn);
    hipLaunchKernelGGL(down4, dim3((unsigned)(quart / 256)), dim3(256), 0, stream, B, Cb); // d1 -> Cb
    hipLaunchKernelGGL(up4, dim3((unsigned)(full / 256)), dim3(256), 0, stream, Cb, A);    // u1 -> A
    hipLaunchKernelGGL(rowop, dim3(NC * H * 2), dim3(256), 0, stream, A, B, gn);           // t3' -> B

    // colOp(t3') + LAM * up(hx) -> out
    hipLaunchKernelGGL(final_k, dim3(NC * H * 2), dim3(256), 0, stream, B, D, out, gn);
}

// Round 2
// 234.213 us; speedup vs baseline: 1.9180x; 1.9180x over previous
//
#include <hip/hip_runtime.h>
#include <math.h>

namespace {

constexpr int W = 2048, H = 2048, NC = 3, HALF = 1024;
constexpr size_t HWSZ = (size_t)W * H;
constexpr float LAM = 0.05f;

__device__ __forceinline__ int refl(int i, int n) {
    return i < 0 ? -1 - i : (i >= n ? 2 * n - 1 - i : i);
}

// gn[i] = g[i]/sum(g) recovered from normalized 2D kernel diagonal
__global__ void prep_gn(const float* __restrict__ k, float* __restrict__ gn) {
    int t = threadIdx.x;
    if (t < 25) gn[t] = sqrtf(k[t * 25 + t]);
}

// ---------------- Branch B: fused 2D antialiased down x2 (x -> hx) ----------------
__global__ __launch_bounds__(256) void bb_down(const float* __restrict__ in,
                                               float* __restrict__ out) {
    int b = blockIdx.x;
    int tx = b & 31;
    int ty = (b >> 5) & 31;
    int c = b >> 10;
    int oi0 = ty * 32, oj0 = tx * 32;
    __shared__ float ins[70][72];
    __shared__ float tmp[70][33];
    const float* base = in + (size_t)c * HWSZ;
    int r0 = 2 * oi0 - 3, c0 = 2 * oj0 - 3;
    for (int idx = threadIdx.x; idx < 70 * 70; idx += 256) {
        int r = idx / 70;
        int cc = idx - r * 70;
        ins[r][cc] = base[(size_t)refl(r0 + r, H) * W + refl(c0 + cc, W)];
    }
    __syncthreads();
    const float WA[8] = {-0.01171875f, -0.03515625f, 0.11328125f, 0.43359375f,
                         0.43359375f,  0.11328125f,  -0.03515625f, -0.01171875f};
    for (int idx = threadIdx.x; idx < 70 * 32; idx += 256) {
        int r = idx >> 5;
        int oc = idx & 31;
        float s = 0.f;
#pragma unroll
        for (int t = 0; t < 8; ++t) s = fmaf(WA[t], ins[r][2 * oc + t], s);
        tmp[r][oc] = s;
    }
    __syncthreads();
    for (int idx = threadIdx.x; idx < 32 * 32; idx += 256) {
        int orr = idx >> 5;
        int oc = idx & 31;
        float s = 0.f;
#pragma unroll
        for (int t = 0; t < 8; ++t) s = fmaf(WA[t], tmp[2 * orr + t][oc], s);
        out[(size_t)c * HALF * HALF + (size_t)(oi0 + orr) * HALF + (oj0 + oc)] = s;
    }
}

// ---------------- Branch A stage 1: horizontal composite conv+down  (x -> t) ------
// t(row, oj) = sum_b wd[b] * Bh(refl(2oj-1+b)), Bh = 25-tap wrap conv of row.
// Interior oj in [1,1022]: 28-tap composite cw. oj==0 / oj==1023 exact path.
__global__ __launch_bounds__(256) void hdown(const float* __restrict__ in,
                                             float* __restrict__ out,
                                             const float* __restrict__ gn) {
    __shared__ float xs[2048 + 256]; // pad map A(j)=j+(j>>3): lane stride 9 -> no conflicts
    int row = blockIdx.x;
    int tid = threadIdx.x;
    const float* r = in + (size_t)row * W;
    float4 v0 = *(const float4*)(r + 4 * tid);
    float4 v1 = *(const float4*)(r + 4 * tid + 1024);
    {
        int j0 = 4 * tid, o0 = j0 + (j0 >> 3);
        xs[o0] = v0.x; xs[o0 + 1] = v0.y; xs[o0 + 2] = v0.z; xs[o0 + 3] = v0.w;
        int j1 = j0 + 1024, o1 = j1 + (j1 >> 3);
        xs[o1] = v1.x; xs[o1 + 1] = v1.y; xs[o1 + 2] = v1.z; xs[o1 + 3] = v1.w;
    }
    __syncthreads();

    float g[25];
#pragma unroll
    for (int p = 0; p < 25; ++p) g[p] = gn[p];
    const float wd0 = -0.0625f, wd1 = 0.5625f;
    float cw[28];
#pragma unroll
    for (int d = 0; d < 28; ++d) {
        float s = 0.f;
        if (d >= 0 && d < 25) s = fmaf(wd0, g[d], s);
        if (d - 1 >= 0 && d - 1 < 25) s = fmaf(wd1, g[d - 1], s);
        if (d - 2 >= 0 && d - 2 < 25) s = fmaf(wd1, g[d - 2], s);
        if (d - 3 >= 0 && d - 3 < 25) s = fmaf(wd0, g[d - 3], s);
        cw[d] = s;
    }

    float xv[34];
    int b0 = 8 * tid - 13;
#pragma unroll
    for (int p = 0; p < 34; ++p) {
        int idx = (b0 + p) & (W - 1);
        xv[p] = xs[idx + (idx >> 3)];
    }
    float a0 = 0.f, a1 = 0.f, a2 = 0.f, a3 = 0.f;
#pragma unroll
    for (int d = 0; d < 28; ++d) {
        float w = cw[d];
        a0 = fmaf(w, xv[d], a0);
        a1 = fmaf(w, xv[d + 2], a1);
        a2 = fmaf(w, xv[d + 4], a2);
        a3 = fmaf(w, xv[d + 6], a3);
    }
    if (tid == 0) { // oj = 0: B indices refl(-1..2) = {0,0,1,2}
        a0 = 0.f;
        const float wdv[4] = {wd0, wd1, wd1, wd0};
#pragma unroll
        for (int a = 0; a < 4; ++a) {
            int jj = refl(-1 + a, W);
            float bh = 0.f;
#pragma unroll
            for (int p = 0; p < 25; ++p) {
                int idx = (jj - 12 + p) & (W - 1);
                bh = fmaf(g[p], xs[idx + (idx >> 3)], bh);
            }
            a0 = fmaf(wdv[a], bh, a0);
        }
    }
    if (tid == 255) { // oj = 1023: B indices {2045,2046,2047,2047}
        a3 = 0.f;
        const float wdv[4] = {wd0, wd1, wd1, wd0};
#pragma unroll
        for (int a = 0; a < 4; ++a) {
            int jj = refl(2045 + a, W);
            float bh = 0.f;
#pragma unroll
            for (int p = 0; p < 25; ++p) {
                int idx = (jj - 12 + p) & (W - 1);
                bh = fmaf(g[p], xs[idx + (idx >> 3)], bh);
            }
            a3 = fmaf(wdv[a], bh, a3);
        }
    }
    *(float4*)(out + (size_t)row * HALF + 4 * tid) = make_float4(a0, a1, a2, a3);
}

// ---------------- Branch A stage 2: vertical composite conv+down  (t -> d1) -------
__global__ __launch_bounds__(256) void vdown(const float* __restrict__ t,
                                             float* __restrict__ d1,
                                             const float* __restrict__ gn) {
    size_t gt = (size_t)blockIdx.x * 256 + threadIdx.x;
    int jv = (int)(gt & 255);
    int oi = (int)((gt >> 8) & (HALF - 1));
    int c = (int)(gt >> 18);
    const float* base = t + (size_t)c * ((size_t)H * HALF) + (size_t)jv * 4;

    float g[25];
#pragma unroll
    for (int p = 0; p < 25; ++p) g[p] = gn[p];
    const float wd0 = -0.0625f, wd1 = 0.5625f;

    float ax = 0.f, ay = 0.f, az = 0.f, aw = 0.f;
    if (oi >= 1 && oi <= HALF - 2) {
        float cw[28];
#pragma unroll
        for (int d = 0; d < 28; ++d) {
            float s = 0.f;
            if (d >= 0 && d < 25) s = fmaf(wd0, g[d], s);
            if (d - 1 >= 0 && d - 1 < 25) s = fmaf(wd1, g[d - 1], s);
            if (d - 2 >= 0 && d - 2 < 25) s = fmaf(wd1, g[d - 2], s);
            if (d - 3 >= 0 && d - 3 < 25) s = fmaf(wd0, g[d - 3], s);
            cw[d] = s;
        }
        int b0 = 2 * oi - 13;
#pragma unroll
        for (int d = 0; d < 28; ++d) {
            float4 v = *(const float4*)(base + (size_t)((b0 + d) & (H - 1)) * HALF);
            float w = cw[d];
            ax = fmaf(w, v.x, ax); ay = fmaf(w, v.y, ay);
            az = fmaf(w, v.z, az); aw = fmaf(w, v.w, aw);
        }
    } else { // oi == 0 or 1023 (uniform per block): exact refl path
        const float wdv[4] = {wd0, wd1, wd1, wd0};
#pragma unroll
        for (int a = 0; a < 4; ++a) {
            int rr = refl(2 * oi - 1 + a, H);
            float bx = 0.f, by = 0.f, bz = 0.f, bw = 0.f;
#pragma unroll
            for (int p = 0; p < 25; ++p) {
                float4 v = *(const float4*)(base + (size_t)((rr - 12 + p) & (H - 1)) * HALF);
                float gg = g[p];
                bx = fmaf(gg, v.x, bx); by = fmaf(gg, v.y, by);
                bz = fmaf(gg, v.z, bz); bw = fmaf(gg, v.w, bw);
            }
            float w = wdv[a];
            ax = fmaf(w, bx, ax); ay = fmaf(w, by, ay);
            az = fmaf(w, bz, az); aw = fmaf(w, bw, aw);
        }
    }
    *(float4*)(d1 + (size_t)c * HALF * HALF + (size_t)oi * HALF + (size_t)jv * 4) =
        make_float4(ax, ay, az, aw);
}

// ---------------- Branch A stage 3: up x2 row + fused shiftH.convH  (d1 -> t3) ----
__global__ __launch_bounds__(256) void uprow(const float* __restrict__ d1,
                                             float* __restrict__ out,
                                             const float* __restrict__ gn) {
    __shared__ float vr[1024 + 128]; // pad map j+(j>>3)
    __shared__ float ur[2048 + 256];
    int i = blockIdx.x & (H - 1);
    int c = blockIdx.x >> 11;
    int tid = threadIdx.x;
    const float WE4[4] = {-0.0234375f, 0.2265625f, 0.8671875f, -0.0703125f};

    // phase 1: vertical up for row i -> vr (1024)
    int par = i & 1;
    int bi = (i >> 1) + par - 2;
    const float* db = d1 + (size_t)c * HALF * HALF;
    float sx = 0.f, sy = 0.f, sz = 0.f, sw = 0.f;
#pragma unroll
    for (int a = 0; a < 4; ++a) {
        float w = par ? WE4[3 - a] : WE4[a];
        float4 v = *(const float4*)(db + (size_t)refl(bi + a, HALF) * HALF + 4 * tid);
        sx = fmaf(w, v.x, sx); sy = fmaf(w, v.y, sy);
        sz = fmaf(w, v.z, sz); sw = fmaf(w, v.w, sw);
    }
    {
        int j0 = 4 * tid, o = j0 + (j0 >> 3);
        vr[o] = sx; vr[o + 1] = sy; vr[o + 2] = sz; vr[o + 3] = sw;
    }
    __syncthreads();

    // phase 2: horizontal up -> ur (2048)
#pragma unroll
    for (int q = 0; q < 8; ++q) {
        int j = 8 * tid + q;
        int bj = (j >> 1) + (j & 1) - 2;
        float u = 0.f;
#pragma unroll
        for (int b = 0; b < 4; ++b) {
            float wb = (j & 1) ? WE4[3 - b] : WE4[b];
            int idx = refl(bj + b, HALF);
            u = fmaf(wb, vr[idx + (idx >> 3)], u);
        }
        ur[j + (j >> 3)] = u;
    }
    __syncthreads();

    // phase 3: 26-tap shifted row conv (wrap), last col clamps to plain 25-tap
    float g[25];
#pragma unroll
    for (int p = 0; p < 25; ++p) g[p] = gn[p];
    float hw[26];
    hw[0] = 0.5f * g[0];
#pragma unroll
    for (int t = 1; t < 25; ++t) hw[t] = 0.5f * (g[t] + g[t - 1]);
    hw[25] = 0.5f * g[24];

    float xv[33];
    int b0 = 8 * tid - 12;
#pragma unroll
    for (int p = 0; p < 33; ++p) {
        int idx = (b0 + p) & (W - 1);
        xv[p] = ur[idx + (idx >> 3)];
    }
    float acc[8] = {0.f, 0.f, 0.f, 0.f, 0.f, 0.f, 0.f, 0.f};
#pragma unroll
    for (int t = 0; t < 26; ++t) {
        float w = hw[t];
#pragma unroll
        for (int q = 0; q < 8; ++q) acc[q] = fmaf(w, xv[t + q], acc[q]);
    }
    if (tid == 255) { // j = 2047: shift clamps -> plain conv
        float a = 0.f;
#pragma unroll
        for (int p = 0; p < 25; ++p) a = fmaf(g[p], xv[p + 7], a);
        acc[7] = a;
    }
    float* ob = out + (size_t)blockIdx.x * W + 8 * tid;
    *(float4*)ob = make_float4(acc[0], acc[1], acc[2], acc[3]);
    *(float4*)(ob + 4) = make_float4(acc[4], acc[5], acc[6], acc[7]);
}

// ---------------- Final: vertical shiftV.convV (register-rolled) + LAM*up(hx) -----
__global__ __launch_bounds__(256, 2) void final_roll(const float* __restrict__ t3,
                                                     const float* __restrict__ hx,
                                                     float* __restrict__ out,
                                                     const float* __restrict__ gn) {
    int b = blockIdx.x;
    int seg = b & 1;
    int rest = b >> 1;
    int ib = rest & 127;
    int c = rest >> 7;
    int i0 = ib * 16;
    int tid = threadIdx.x;
    int j0 = seg * 1024 + tid * 4;

    float g[25];
#pragma unroll
    for (int p = 0; p < 25; ++p) g[p] = gn[p];
    float hw[26];
    hw[0] = 0.5f * g[0];
#pragma unroll
    for (int t = 1; t < 25; ++t) hw[t] = 0.5f * (g[t] + g[t - 1]);
    hw[25] = 0.5f * g[24];

    const float* tb = t3 + (size_t)c * HWSZ + j0;
    float4 acc[16];
#pragma unroll
    for (int k = 0; k < 16; ++k) acc[k] = make_float4(0.f, 0.f, 0.f, 0.f);

#pragma unroll
    for (int d = 0; d < 41; ++d) {
        float4 v = *(const float4*)(tb + (size_t)((i0 - 12 + d) & (H - 1)) * W);
#pragma unroll
        for (int k = 0; k < 16; ++k) {
            int tt = d - k;
            if (tt >= 0 && tt < 26) {
                float w = hw[tt];
                acc[k].x = fmaf(w, v.x, acc[k].x);
                acc[k].y = fmaf(w, v.y, acc[k].y);
                acc[k].z = fmaf(w, v.z, acc[k].z);
                acc[k].w = fmaf(w, v.w, acc[k].w);
            }
        }
    }
    if (i0 == H - 16) { // row 2047: shift clamps -> plain 25-tap conv
        float4 a = make_float4(0.f, 0.f, 0.f, 0.f);
#pragma unroll
        for (int p = 0; p < 25; ++p) {
            float4 v = *(const float4*)(tb + (size_t)((H - 1 - 12 + p) & (H - 1)) * W);
            float gg = g[p];
            a.x = fmaf(gg, v.x, a.x); a.y = fmaf(gg, v.y, a.y);
            a.z = fmaf(gg, v.z, a.z); a.w = fmaf(gg, v.w, a.w);
        }
        acc[15] = a;
    }

    // fused LAM * bicubic-up of hx over 16 rows x 4 cols
    const float WE4[4] = {-0.0234375f, 0.2265625f, 0.8671875f, -0.0703125f};
    int ih0 = i0 >> 1;
    int c0 = (j0 >> 1) - 2;
    int rc[6];
#pragma unroll
    for (int bq = 0; bq < 6; ++bq) rc[bq] = refl(c0 + bq, HALF);
    const float* hb = hx + (size_t)c * HALF * HALF;
#pragma unroll
    for (int m = 0; m < 12; ++m) {
        const float* hr = hb + (size_t)refl(ih0 - 2 + m, HALF) * HALF;
        float v0 = hr[rc[0]], v1 = hr[rc[1]], v2 = hr[rc[2]];
        float v3 = hr[rc[3]], v4 = hr[rc[4]], v5 = hr[rc[5]];
        float s0 = WE4[0] * v0 + WE4[1] * v1 + WE4[2] * v2 + WE4[3] * v3;
        float s1 = WE4[3] * v1 + WE4[2] * v2 + WE4[1] * v3 + WE4[0] * v4;
        float s2 = WE4[0] * v1 + WE4[1] * v2 + WE4[2] * v3 + WE4[3] * v4;
        float s3 = WE4[3] * v2 + WE4[2] * v3 + WE4[1] * v4 + WE4[0] * v5;
#pragma unroll
        for (int k = 0; k < 16; ++k) {
            int bik = (k >> 1) + (k & 1) - 2;
            int aa = m - 2 - bik;
            if (aa >= 0 && aa < 4) {
                float w = LAM * ((k & 1) ? WE4[3 - aa] : WE4[aa]);
                acc[k].x = fmaf(w, s0, acc[k].x);
                acc[k].y = fmaf(w, s1, acc[k].y);
                acc[k].z = fmaf(w, s2, acc[k].z);
                acc[k].w = fmaf(w, s3, acc[k].w);
            }
        }
    }

    float* ob = out + (size_t)c * HWSZ + j0;
#pragma unroll
    for (int k = 0; k < 16; ++k)
        *(float4*)(ob + (size_t)(i0 + k) * W) = acc[k];
}

} // namespace

extern "C" void kernel_launch(void* const* d_in, const int* in_sizes, int n_in,
                              void* d_out, int out_size, void* d_ws, size_t ws_size,
                              hipStream_t stream) {
    const float* x = (const float*)d_in[0]; // (1,3,2048,2048) f32
    const float* k = (const float*)d_in[1]; // (25,25) f32
    float* ws = (float*)d_ws;
    float* out = (float*)d_out;

    const size_t full = (size_t)NC * HWSZ;           // 12,582,912
    const size_t halfrow = (size_t)NC * H * HALF;    // 6,291,456
    const size_t quart = (size_t)NC * HALF * HALF;   // 3,145,728

    float* t = ws;             // halfrow
    float* d1 = t + halfrow;   // quart
    float* t3 = d1 + quart;    // full
    float* hxp = t3 + full;    // quart
    float* gn = hxp + quart;   // 25 floats

    hipLaunchKernelGGL(prep_gn, dim3(1), dim3(64), 0, stream, k, gn);
    hipLaunchKernelGGL(bb_down, dim3(32 * 32 * NC), dim3(256), 0, stream, x, hxp);
    hipLaunchKernelGGL(hdown, dim3(NC * H), dim3(256), 0, stream, x, t, gn);
    hipLaunchKernelGGL(vdown, dim3((unsigned)((quart / 4) / 256)), dim3(256), 0, stream, t, d1, gn);
    hipLaunchKernelGGL(uprow, dim3(NC * H), dim3(256), 0, stream, d1, t3, gn);
    hipLaunchKernelGGL(final_roll, dim3(NC * 128 * 2), dim3(256), 0, stream, t3, hxp, out, gn);
}

// Round 3
// 179.942 us; speedup vs baseline: 2.4965x; 1.3016x over previous
//
#include <hip/hip_runtime.h>
#include <math.h>

namespace {

constexpr int W = 2048, H = 2048, NC = 3, HALF = 1024;
constexpr size_t HWSZ = (size_t)W * H;
constexpr size_t MQ = (size_t)HALF * HALF;
constexpr size_t M2 = 2 * MQ;
constexpr float LAM = 0.05f;

__device__ __forceinline__ int refl(int i, int n) {
    return i < 0 ? -1 - i : (i >= n ? 2 * n - 1 - i : i);
}

__global__ void prep_gn(const float* __restrict__ k, float* __restrict__ gn) {
    int t = threadIdx.x;
    if (t < 25) gn[t] = sqrtf(k[t * 25 + t]);
}

__device__ __forceinline__ void load_g(const float* __restrict__ gnp, float* g) {
#pragma unroll
    for (int p = 0; p < 25; ++p) g[p] = gnp[p];
}

__device__ __forceinline__ void build_hw(const float* g, float* hw) {
    hw[0] = 0.5f * g[0];
#pragma unroll
    for (int t = 1; t < 25; ++t) hw[t] = 0.5f * (g[t] + g[t - 1]);
    hw[25] = 0.5f * g[24];
}

__device__ __forceinline__ void build_cw(const float* g, float* cw) {
#pragma unroll
    for (int d = 0; d < 28; ++d) {
        float s = 0.f;
        if (d < 25) s = fmaf(-0.0625f, g[d], s);
        if (d >= 1 && d <= 25) s = fmaf(0.5625f, g[d - 1], s);
        if (d >= 2 && d <= 26) s = fmaf(0.5625f, g[d - 2], s);
        if (d >= 3) s = fmaf(-0.0625f, g[d - 3], s);
        cw[d] = s;
    }
}

// composite of (26-tap shifted conv at full-res) ∘ (bicubic up x2): 17 taps/parity
__device__ __forceinline__ void build_CW(const float* hw, float* C0, float* C1) {
    const float WE4[4] = {-0.0234375f, 0.2265625f, 0.8671875f, -0.0703125f};
#pragma unroll
    for (int m = 0; m < 17; ++m) { C0[m] = 0.f; C1[m] = 0.f; }
#pragma unroll
    for (int p = 0; p < 2; ++p) {
#pragma unroll
        for (int t = 0; t < 26; ++t) {
            int r = p - 12 + t;
            int fl = (r + 64) / 2 - 32;
            int e = (r + 64) & 1;
#pragma unroll
            for (int b = 0; b < 4; ++b) {
                int m = fl + e + b - 2 + 8;
                float wub = e ? WE4[3 - b] : WE4[b];
                float add = hw[t] * wub;
                if (p == 0) C0[m] += add;
                else C1[m] += add;
            }
        }
    }
}

// ---- front: x -> d1 (conv+down composite both axes) AND x -> hx (AA down) ----
__global__ __launch_bounds__(256) void front(const float* __restrict__ x,
                                             float* __restrict__ d1,
                                             float* __restrict__ hx,
                                             const float* __restrict__ gnp) {
    __shared__ float xs[90][92];
    __shared__ float th[90][33];
    int b = blockIdx.x;
    int tx = b & 31, ty = (b >> 5) & 31, c = b >> 10;
    int tid = threadIdx.x;
    int r0 = 64 * ty - 13, c0 = 64 * tx - 13;
    const float* xb = x + (size_t)c * HWSZ;
    for (int idx = tid; idx < 8100; idx += 256) {
        int r = idx / 90, cc = idx - 90 * r;
        xs[r][cc] = xb[(size_t)((r0 + r) & 2047) * W + ((c0 + cc) & 2047)];
    }
    float g[25]; load_g(gnp, g);
    float cw[28]; build_cw(g, cw);
    __syncthreads();

    // branch B: AA down x2 using th as tmp
    const float WA[8] = {-0.01171875f, -0.03515625f, 0.11328125f, 0.43359375f,
                         0.43359375f,  0.11328125f,  -0.03515625f, -0.01171875f};
    int ob_r0 = 64 * ty - 3;
    int ob_c0 = 64 * tx - 3;
    for (int idx = tid; idx < 560; idx += 256) {
        int rr = idx >> 3, g4 = idx & 7;
        int lr = refl(ob_r0 + rr, H) - r0;
        const float* xr = &xs[lr][0];
        float a0 = 0.f, a1 = 0.f, a2 = 0.f, a3 = 0.f;
#pragma unroll
        for (int u = 0; u < 14; ++u) {
            int lc = refl(ob_c0 + 8 * g4 + u, W) - c0;
            float v = xr[lc];
            if (u < 8) a0 = fmaf(WA[u], v, a0);
            if (u >= 2 && u < 10) a1 = fmaf(WA[u - 2], v, a1);
            if (u >= 4 && u < 12) a2 = fmaf(WA[u - 4], v, a2);
            if (u >= 6) a3 = fmaf(WA[u - 6], v, a3);
        }
        th[rr][4 * g4 + 0] = a0;
        th[rr][4 * g4 + 1] = a1;
        th[rr][4 * g4 + 2] = a2;
        th[rr][4 * g4 + 3] = a3;
    }
    __syncthreads();
    for (int idx = tid; idx < 1024; idx += 256) {
        int orr = idx >> 5, oc = idx & 31;
        float s = 0.f;
#pragma unroll
        for (int t = 0; t < 8; ++t) s = fmaf(WA[t], th[2 * orr + t][oc], s);
        hx[(size_t)c * MQ + (size_t)(32 * ty + orr) * HALF + 32 * tx + oc] = s;
    }
    __syncthreads();

    // phase 1: horizontal composite -> th
    for (int idx = tid; idx < 720; idx += 256) {
        int r = idx >> 3, g4 = idx & 7;
        const float* xr = &xs[r][8 * g4];
        float a0 = 0.f, a1 = 0.f, a2 = 0.f, a3 = 0.f;
#pragma unroll
        for (int u = 0; u < 34; ++u) {
            float v = xr[u];
            if (u < 28) a0 = fmaf(cw[u], v, a0);
            if (u >= 2 && u < 30) a1 = fmaf(cw[u - 2], v, a1);
            if (u >= 4 && u < 32) a2 = fmaf(cw[u - 4], v, a2);
            if (u >= 6) a3 = fmaf(cw[u - 6], v, a3);
        }
        th[r][4 * g4 + 0] = a0;
        th[r][4 * g4 + 1] = a1;
        th[r][4 * g4 + 2] = a2;
        th[r][4 * g4 + 3] = a3;
    }
    __syncthreads();
    if (tx == 0) {
        for (int r = tid; r < 90; r += 256) {
            float b0 = 0.f, b1 = 0.f, b2 = 0.f;
#pragma unroll
            for (int p = 0; p < 25; ++p) {
                b0 = fmaf(g[p], xs[r][1 + p], b0);
                b1 = fmaf(g[p], xs[r][2 + p], b1);
                b2 = fmaf(g[p], xs[r][3 + p], b2);
            }
            th[r][0] = 0.5f * b0 + 0.5625f * b1 - 0.0625f * b2;
        }
    }
    if (tx == 31) {
        for (int r = tid; r < 90; r += 256) {
            float b0 = 0.f, b1 = 0.f, b2 = 0.f;
#pragma unroll
            for (int p = 0; p < 25; ++p) {
                b0 = fmaf(g[p], xs[r][62 + p], b0);
                b1 = fmaf(g[p], xs[r][63 + p], b1);
                b2 = fmaf(g[p], xs[r][64 + p], b2);
            }
            th[r][31] = -0.0625f * b0 + 0.5625f * b1 + 0.5f * b2;
        }
    }
    __syncthreads();

    // phase 2: vertical composite -> d1
    {
        int oc = tid & 31, v4 = tid >> 5;
        float a0 = 0.f, a1 = 0.f, a2 = 0.f, a3 = 0.f;
#pragma unroll
        for (int u = 0; u < 34; ++u) {
            float v = th[8 * v4 + u][oc];
            if (u < 28) a0 = fmaf(cw[u], v, a0);
            if (u >= 2 && u < 30) a1 = fmaf(cw[u - 2], v, a1);
            if (u >= 4 && u < 32) a2 = fmaf(cw[u - 4], v, a2);
            if (u >= 6) a3 = fmaf(cw[u - 6], v, a3);
        }
        float av[4] = {a0, a1, a2, a3};
        if (ty == 0 && v4 == 0) {
            float b0 = 0.f, b1 = 0.f, b2 = 0.f;
#pragma unroll
            for (int p = 0; p < 25; ++p) {
                b0 = fmaf(g[p], th[1 + p][oc], b0);
                b1 = fmaf(g[p], th[2 + p][oc], b1);
                b2 = fmaf(g[p], th[3 + p][oc], b2);
            }
            av[0] = 0.5f * b0 + 0.5625f * b1 - 0.0625f * b2;
        }
        if (ty == 31 && v4 == 7) {
            float b0 = 0.f, b1 = 0.f, b2 = 0.f;
#pragma unroll
            for (int p = 0; p < 25; ++p) {
                b0 = fmaf(g[p], th[62 + p][oc], b0);
                b1 = fmaf(g[p], th[63 + p][oc], b1);
                b2 = fmaf(g[p], th[64 + p][oc], b2);
            }
            av[3] = -0.0625f * b0 + 0.5625f * b1 + 0.5f * b2;
        }
        float* dp = d1 + (size_t)c * MQ + (size_t)(32 * ty + 4 * v4) * HALF + 32 * tx + oc;
#pragma unroll
        for (int k = 0; k < 4; ++k) dp[(size_t)k * HALF] = av[k];
    }
}

// ---- a_main: d1 -> m1 (vertical 17-tap composite, interior rows) ----
__global__ __launch_bounds__(256) void a_main(const float* __restrict__ d1,
                                              float* __restrict__ m1,
                                              const float* __restrict__ gnp) {
    int bid = blockIdx.x;
    int ib = bid & 255, c = bid >> 8;
    int tid = threadIdx.x;
    float g[25]; load_g(gnp, g);
    float hw[26]; build_hw(g, hw);
    float C0[17], C1[17]; build_CW(hw, C0, C1);
    int i0 = 8 * ib, q0 = 4 * ib;
    const float* dp = d1 + ((long long)c * (long long)MQ + (long long)(q0 - 8) * HALF + 4 * tid);
    float4 acc[8];
#pragma unroll
    for (int k = 0; k < 8; ++k) acc[k] = make_float4(0.f, 0.f, 0.f, 0.f);
#pragma unroll
    for (int d = 0; d < 20; ++d) {
        float4 v = *(const float4*)(dp + (long long)d * HALF);
#pragma unroll
        for (int k = 0; k < 8; ++k) {
            int m = d - (k >> 1);
            if (m >= 0 && m < 17) {
                float wgt = (k & 1) ? C1[m] : C0[m];
                acc[k].x = fmaf(wgt, v.x, acc[k].x);
                acc[k].y = fmaf(wgt, v.y, acc[k].y);
                acc[k].z = fmaf(wgt, v.z, acc[k].z);
                acc[k].w = fmaf(wgt, v.w, acc[k].w);
            }
        }
    }
    float* mp = m1 + (size_t)c * M2 + (size_t)i0 * HALF + 4 * tid;
#pragma unroll
    for (int k = 0; k < 8; ++k) *(float4*)(mp + (size_t)k * HALF) = acc[k];
}

// ---- a_border: exact m1 rows [0,16) u [2032,2048) ----
__global__ __launch_bounds__(256) void a_border(const float* __restrict__ d1,
                                                float* __restrict__ m1,
                                                const float* __restrict__ gnp) {
    int bid = blockIdx.x;
    int ri = bid & 31, c = bid >> 5;
    int i = ri < 16 ? ri : 2016 + ri;
    int tid = threadIdx.x;
    float g[25]; load_g(gnp, g);
    float hw[26]; build_hw(g, hw);
    const float WE4[4] = {-0.0234375f, 0.2265625f, 0.8671875f, -0.0703125f};
    bool cl = (i == 2047);
    const float* db = d1 + (size_t)c * MQ + 4 * tid;
    float4 a = make_float4(0.f, 0.f, 0.f, 0.f);
#pragma unroll
    for (int t = 0; t < 26; ++t) {
        float wgt = cl ? (t < 25 ? g[t] : 0.f) : hw[t];
        int ip = (i - 12 + t) & 2047;
        int e = ip & 1, qq = (ip >> 1) + e - 2;
        float4 uv = make_float4(0.f, 0.f, 0.f, 0.f);
#pragma unroll
        for (int bq = 0; bq < 4; ++bq) {
            float wu = e ? WE4[3 - bq] : WE4[bq];
            int rr = refl(qq + bq, HALF);
            float4 v = *(const float4*)(db + (size_t)rr * HALF);
            uv.x = fmaf(wu, v.x, uv.x);
            uv.y = fmaf(wu, v.y, uv.y);
            uv.z = fmaf(wu, v.z, uv.z);
            uv.w = fmaf(wu, v.w, uv.w);
        }
        a.x = fmaf(wgt, uv.x, a.x);
        a.y = fmaf(wgt, uv.y, a.y);
        a.z = fmaf(wgt, uv.z, a.z);
        a.w = fmaf(wgt, uv.w, a.w);
    }
    *(float4*)(m1 + (size_t)c * M2 + (size_t)i * HALF + 4 * tid) = a;
}

// ---- b_main: m1,hx -> out (horizontal composite + LAM*up(hx)) ----
__global__ __launch_bounds__(256) void b_main(const float* __restrict__ m1,
                                              const float* __restrict__ hx,
                                              float* __restrict__ out,
                                              const float* __restrict__ gnp) {
    __shared__ float mr[4][1040];
    __shared__ float hv[4][1040];
    int bid = blockIdx.x;
    int rb = bid & 511, c = bid >> 9;
    int tid = threadIdx.x;
    float g[25]; load_g(gnp, g);
    float hw[26]; build_hw(g, hw);
    float C0[17], C1[17]; build_CW(hw, C0, C1);
    const float WE4[4] = {-0.0234375f, 0.2265625f, 0.8671875f, -0.0703125f};
    int i0 = 4 * rb;
    const float* mb = m1 + (size_t)c * M2 + (size_t)i0 * HALF;
#pragma unroll
    for (int r = 0; r < 4; ++r) {
        float4 v = *(const float4*)(mb + (size_t)r * HALF + 4 * tid);
        *(float4*)&mr[r][8 + 4 * tid] = v;
    }
    const float* hb = hx + (size_t)c * MQ;
    int q2 = 2 * rb;
#pragma unroll
    for (int k = 0; k < 4; ++k) {
        float4 a = make_float4(0.f, 0.f, 0.f, 0.f);
#pragma unroll
        for (int aq = 0; aq < 4; ++aq) {
            float wu = (k & 1) ? WE4[3 - aq] : WE4[aq];
            int row = refl(q2 - 2 + (k >> 1) + (k & 1) + aq, HALF);
            float4 v = *(const float4*)(hb + (size_t)row * HALF + 4 * tid);
            a.x = fmaf(wu, v.x, a.x);
            a.y = fmaf(wu, v.y, a.y);
            a.z = fmaf(wu, v.z, a.z);
            a.w = fmaf(wu, v.w, a.w);
        }
        *(float4*)&hv[k][4 + 4 * tid] = a;
        if (tid == 0) { hv[k][3] = a.x; hv[k][2] = a.y; }
        if (tid == 255) { hv[k][4 + 1024] = a.w; hv[k][4 + 1025] = a.z; }
    }
    __syncthreads();
    float* ob = out + (size_t)c * HWSZ + (size_t)i0 * W + 8 * tid;
#pragma unroll
    for (int r = 0; r < 4; ++r) {
        float w[20];
#pragma unroll
        for (int q5 = 0; q5 < 5; ++q5)
            *(float4*)&w[4 * q5] = *(const float4*)&mr[r][4 * tid + 4 * q5];
        float wv[12];
#pragma unroll
        for (int q3 = 0; q3 < 3; ++q3)
            *(float4*)&wv[4 * q3] = *(const float4*)&hv[r][4 * tid + 4 * q3];
        float res[8];
#pragma unroll
        for (int s = 0; s < 8; ++s) {
            int h = s >> 1;
            float a = 0.f;
#pragma unroll
            for (int m = 0; m < 17; ++m)
                a = fmaf((s & 1) ? C1[m] : C0[m], w[h + m], a);
            float uh = 0.f;
#pragma unroll
            for (int bq = 0; bq < 4; ++bq)
                uh = fmaf((s & 1) ? WE4[3 - bq] : WE4[bq], wv[h + (s & 1) + 2 + bq], uh);
            res[s] = fmaf(LAM, uh, a);
        }
        *(float4*)(ob + (size_t)r * W) = make_float4(res[0], res[1], res[2], res[3]);
        *(float4*)(ob + (size_t)r * W + 4) = make_float4(res[4], res[5], res[6], res[7]);
    }
}

// ---- b_border: exact out cols [0,16) u [2032,2048), all rows ----
__global__ __launch_bounds__(256) void b_border(const float* __restrict__ m1,
                                                const float* __restrict__ hx,
                                                float* __restrict__ out,
                                                const float* __restrict__ gnp) {
    int bid = blockIdx.x;
    int rg = bid & 255, c = bid >> 8;
    int tid = threadIdx.x;
    int i = 8 * rg + (tid >> 5);
    int cc = tid & 31;
    int j = cc < 16 ? cc : 2016 + cc;
    float g[25]; load_g(gnp, g);
    float hw[26]; build_hw(g, hw);
    const float WE4[4] = {-0.0234375f, 0.2265625f, 0.8671875f, -0.0703125f};
    const float* mrow = m1 + (size_t)c * M2 + (size_t)i * HALF;
    bool cl = (j == 2047);
    float val = 0.f;
#pragma unroll
    for (int t = 0; t < 26; ++t) {
        float wgt = cl ? (t < 25 ? g[t] : 0.f) : hw[t];
        int jp = (j - 12 + t) & 2047;
        int e = jp & 1;
        int qq = (jp >> 1) + e - 2;
        float uh = 0.f;
#pragma unroll
        for (int bq = 0; bq < 4; ++bq)
            uh = fmaf(e ? WE4[3 - bq] : WE4[bq], mrow[refl(qq + bq, HALF)], uh);
        val = fmaf(wgt, uh, val);
    }
    const float* hb = hx + (size_t)c * MQ;
    int qi = (i >> 1) + (i & 1) - 2;
    int qj = (j >> 1) + (j & 1) - 2;
    float hval = 0.f;
#pragma unroll
    for (int aq = 0; aq < 4; ++aq) {
        const float* hr = hb + (size_t)refl(qi + aq, HALF) * HALF;
        float rowa = (i & 1) ? WE4[3 - aq] : WE4[aq];
        float s = 0.f;
#pragma unroll
        for (int bq = 0; bq < 4; ++bq)
            s = fmaf((j & 1) ? WE4[3 - bq] : WE4[bq], hr[refl(qj + bq, HALF)], s);
        hval = fmaf(rowa, s, hval);
    }
    out[(size_t)c * HWSZ + (size_t)i * W + j] = fmaf(LAM, hval, val);
}

} // namespace

extern "C" void kernel_launch(void* const* d_in, const int* in_sizes, int n_in,
                              void* d_out, int out_size, void* d_ws, size_t ws_size,
                              hipStream_t stream) {
    (void)in_sizes; (void)n_in; (void)out_size; (void)ws_size;
    const float* x = (const float*)d_in[0];
    const float* k = (const float*)d_in[1];
    float* ws = (float*)d_ws;
    float* out = (float*)d_out;

    float* hxp = ws;                    // 3*MQ
    float* d1 = hxp + 3 * MQ;           // 3*MQ
    float* m1 = d1 + 3 * MQ;            // 3*M2
    float* gn = m1 + 3 * M2;            // 25

    hipLaunchKernelGGL(prep_gn, dim3(1), dim3(64), 0, stream, k, gn);
    hipLaunchKernelGGL(front, dim3(32 * 32 * NC), dim3(256), 0, stream, x, d1, hxp, gn);
    hipLaunchKernelGGL(a_main, dim3(256 * NC), dim3(256), 0, stream, d1, m1, gn);
    hipLaunchKernelGGL(a_border, dim3(32 * NC), dim3(256), 0, stream, d1, m1, gn);
    hipLaunchKernelGGL(b_main, dim3(512 * NC), dim3(256), 0, stream, m1, hxp, out, gn);
    hipLaunchKernelGGL(b_border, dim3(256 * NC), dim3(256), 0, stream, m1, hxp, out, gn);
}

// Round 5
// 162.778 us; speedup vs baseline: 2.7598x; 1.1054x over previous
//
#include <hip/hip_runtime.h>
#include <math.h>

namespace {

constexpr int W = 2048, H = 2048, NC = 3, HALF = 1024;
constexpr size_t HWSZ = (size_t)W * H;
constexpr size_t MQ = (size_t)HALF * HALF;
constexpr size_t M2 = 2 * MQ;
constexpr float LAM = 0.05f;

__device__ __forceinline__ int refl(int i, int n) {
    return i < 0 ? -1 - i : (i >= n ? 2 * n - 1 - i : i);
}

// cf layout: [0..24]=g, [32..57]=hw(26), [64..91]=cw(28), [96..112]=C0(17), [128..144]=C1(17)
__global__ void prep(const float* __restrict__ k, float* __restrict__ cf) {
    if (threadIdx.x != 0) return;
    float g[25];
#pragma unroll
    for (int p = 0; p < 25; ++p) { g[p] = sqrtf(k[p * 25 + p]); cf[p] = g[p]; }
    float hw[26];
    hw[0] = 0.5f * g[0];
#pragma unroll
    for (int t = 1; t < 25; ++t) hw[t] = 0.5f * (g[t] + g[t - 1]);
    hw[25] = 0.5f * g[24];
#pragma unroll
    for (int t = 0; t < 26; ++t) cf[32 + t] = hw[t];
#pragma unroll
    for (int d = 0; d < 28; ++d) {
        float s = 0.f;
        if (d < 25) s = fmaf(-0.0625f, g[d], s);
        if (d >= 1 && d <= 25) s = fmaf(0.5625f, g[d - 1], s);
        if (d >= 2 && d <= 26) s = fmaf(0.5625f, g[d - 2], s);
        if (d >= 3) s = fmaf(-0.0625f, g[d - 3], s);
        cf[64 + d] = s;
    }
    const float WE4[4] = {-0.0234375f, 0.2265625f, 0.8671875f, -0.0703125f};
    float C0[17], C1[17];
#pragma unroll
    for (int m = 0; m < 17; ++m) { C0[m] = 0.f; C1[m] = 0.f; }
#pragma unroll
    for (int p = 0; p < 2; ++p) {
#pragma unroll
        for (int t = 0; t < 26; ++t) {
            int r = p - 12 + t;
            int fl = (r + 64) / 2 - 32;
            int e = (r + 64) & 1;
#pragma unroll
            for (int b = 0; b < 4; ++b) {
                int m = fl + e + b - 2 + 8;
                float wub = e ? WE4[3 - b] : WE4[b];
                float add = hw[t] * wub;
                if (p == 0) C0[m] += add;
                else C1[m] += add;
            }
        }
    }
#pragma unroll
    for (int m = 0; m < 17; ++m) { cf[96 + m] = C0[m]; cf[128 + m] = C1[m]; }
}

// ---- front: x -> d1 (composite conv+down both axes) AND x -> hx (AA down) ----
__global__ __launch_bounds__(256) void front(const float* __restrict__ x,
                                             float* __restrict__ d1,
                                             float* __restrict__ hx,
                                             const float* __restrict__ cf) {
    __shared__ float xs[90][97];   // stride 97 == 1 mod 32: (r=idx>>3,q=idx&7) maps 2-way free
    __shared__ float th[90][33];
    int b = blockIdx.x;
    int tx = b & 31, ty = (b >> 5) & 31, c = b >> 10;
    int tid = threadIdx.x;
    const int r0 = 64 * ty - 13;
    const int c0 = 64 * tx - 16;   // 16B aligned loads
    const float* xb = x + (size_t)c * HWSZ;
    // load 90 rows x 24 float4 (96 cols), wrap addressing, div-free
    // mapping: xs[r][cc] = x[(r0+r)&2047][(c0+cc)&2047]
    {
        int lane8 = tid & 7;
        int rsub = tid >> 3; // 0..31
#pragma unroll
        for (int rp = 0; rp < 3; ++rp) {
            int r = rp * 32 + rsub;
            if (r < 90) {
                const float* xr = xb + (size_t)((r0 + r) & 2047) * W;
#pragma unroll
                for (int g4 = 0; g4 < 3; ++g4) {
                    int cc = g4 * 8 + lane8; // 0..23
                    float4 v = *(const float4*)(xr + ((c0 + 4 * cc) & 2047));
                    xs[r][4 * cc + 0] = v.x; xs[r][4 * cc + 1] = v.y;
                    xs[r][4 * cc + 2] = v.z; xs[r][4 * cc + 3] = v.w;
                }
            }
        }
    }
    float g[25], cw[28];
#pragma unroll
    for (int p = 0; p < 25; ++p) g[p] = cf[p];
#pragma unroll
    for (int d = 0; d < 28; ++d) cw[d] = cf[64 + d];
    const bool BROW = (ty == 0 || ty == 31);
    const bool BCOL = (tx == 0 || tx == 31);
    __syncthreads();

    // ---- branch B: AA down. h pass -> th[70][32]
    const float WA[8] = {-0.01171875f, -0.03515625f, 0.11328125f, 0.43359375f,
                         0.43359375f,  0.11328125f,  -0.03515625f, -0.01171875f};
    const int ob_r0 = 64 * ty - 3, ob_c0 = 64 * tx - 3;
    for (int idx = tid; idx < 560; idx += 256) {
        int rr = idx >> 3, q = idx & 7;
        int lr = BROW ? (refl(ob_r0 + rr, H) - r0) : (rr + 10);
        const float* xr = &xs[lr][0];
        float a0 = 0.f, a1 = 0.f, a2 = 0.f, a3 = 0.f;
        if (!BCOL) {
            const float* xp = xr + 13 + 8 * q;
#pragma unroll
            for (int u = 0; u < 14; ++u) {
                float v = xp[u];
                if (u < 8) a0 = fmaf(WA[u], v, a0);
                if (u >= 2 && u < 10) a1 = fmaf(WA[u - 2], v, a1);
                if (u >= 4 && u < 12) a2 = fmaf(WA[u - 4], v, a2);
                if (u >= 6) a3 = fmaf(WA[u - 6], v, a3);
            }
        } else {
#pragma unroll
            for (int u = 0; u < 14; ++u) {
                float v = xr[refl(ob_c0 + 8 * q + u, W) - c0];
                if (u < 8) a0 = fmaf(WA[u], v, a0);
                if (u >= 2 && u < 10) a1 = fmaf(WA[u - 2], v, a1);
                if (u >= 4 && u < 12) a2 = fmaf(WA[u - 4], v, a2);
                if (u >= 6) a3 = fmaf(WA[u - 6], v, a3);
            }
        }
        th[rr][4 * q + 0] = a0;
        th[rr][4 * q + 1] = a1;
        th[rr][4 * q + 2] = a2;
        th[rr][4 * q + 3] = a3;
    }
    __syncthreads();
    // AA v pass -> hx (each thread 4 rows x 1 col, rolling)
    {
        int oc = tid & 31, og = tid >> 5;
        float a0 = 0.f, a1 = 0.f, a2 = 0.f, a3 = 0.f;
#pragma unroll
        for (int u = 0; u < 14; ++u) {
            float v = th[8 * og + u][oc];
            if (u < 8) a0 = fmaf(WA[u], v, a0);
            if (u >= 2 && u < 10) a1 = fmaf(WA[u - 2], v, a1);
            if (u >= 4 && u < 12) a2 = fmaf(WA[u - 4], v, a2);
            if (u >= 6) a3 = fmaf(WA[u - 6], v, a3);
        }
        float* hp = hx + (size_t)c * MQ + (size_t)(32 * ty + 4 * og) * HALF + 32 * tx + oc;
        hp[0] = a0; hp[HALF] = a1; hp[2 * HALF] = a2; hp[3 * HALF] = a3;
    }
    __syncthreads();

    // ---- branch A phase 1: horizontal composite -> th[90][32]
    for (int idx = tid; idx < 720; idx += 256) {
        int r = idx >> 3, q = idx & 7;
        const float* xp = &xs[r][8 * q + 3];
        float a0 = 0.f, a1 = 0.f, a2 = 0.f, a3 = 0.f;
#pragma unroll
        for (int u = 0; u < 34; ++u) {
            float v = xp[u];
            if (u < 28) a0 = fmaf(cw[u], v, a0);
            if (u >= 2 && u < 30) a1 = fmaf(cw[u - 2], v, a1);
            if (u >= 4 && u < 32) a2 = fmaf(cw[u - 4], v, a2);
            if (u >= 6) a3 = fmaf(cw[u - 6], v, a3);
        }
        th[r][4 * q + 0] = a0;
        th[r][4 * q + 1] = a1;
        th[r][4 * q + 2] = a2;
        th[r][4 * q + 3] = a3;
    }
    __syncthreads();
    // exact border columns. wrap taps are present in the tile because the
    // tile load itself wraps (&2047):
    //   tx==0:  x[jj-12+p mod 2048] is at xs local col (jj + p + 4)
    //   tx==31: x[(2045+jj')-12+p mod 2048] is at local col (jj' + p + 65)
    if (tx == 0) {
        for (int r = tid; r < 90; r += 256) {
            float b0 = 0.f, b1 = 0.f, b2 = 0.f;
#pragma unroll
            for (int p = 0; p < 25; ++p) {
                b0 = fmaf(g[p], xs[r][p + 4], b0);
                b1 = fmaf(g[p], xs[r][p + 5], b1);
                b2 = fmaf(g[p], xs[r][p + 6], b2);
            }
            th[r][0] = 0.5f * b0 + 0.5625f * b1 - 0.0625f * b2;
        }
    }
    if (tx == 31) {
        for (int r = tid; r < 90; r += 256) {
            float b0 = 0.f, b1 = 0.f, b2 = 0.f;
#pragma unroll
            for (int p = 0; p < 25; ++p) {
                b0 = fmaf(g[p], xs[r][p + 65], b0);
                b1 = fmaf(g[p], xs[r][p + 66], b1);
                b2 = fmaf(g[p], xs[r][p + 67], b2);
            }
            th[r][31] = -0.0625f * b0 + 0.5625f * b1 + 0.5f * b2;
        }
    }
    __syncthreads();

    // ---- branch A phase 2: vertical composite -> d1 (each thread 4 rows x 1 col)
    {
        int oc = tid & 31, og = tid >> 5;
        float a0 = 0.f, a1 = 0.f, a2 = 0.f, a3 = 0.f;
#pragma unroll
        for (int u = 0; u < 34; ++u) {
            float v = th[8 * og + u][oc];
            if (u < 28) a0 = fmaf(cw[u], v, a0);
            if (u >= 2 && u < 30) a1 = fmaf(cw[u - 2], v, a1);
            if (u >= 4 && u < 32) a2 = fmaf(cw[u - 4], v, a2);
            if (u >= 6) a3 = fmaf(cw[u - 6], v, a3);
        }
        float av[4] = {a0, a1, a2, a3};
        if (ty == 0 && og == 0) {
            float b0 = 0.f, b1 = 0.f, b2 = 0.f;
#pragma unroll
            for (int p = 0; p < 25; ++p) {
                b0 = fmaf(g[p], th[1 + p][oc], b0);
                b1 = fmaf(g[p], th[2 + p][oc], b1);
                b2 = fmaf(g[p], th[3 + p][oc], b2);
            }
            av[0] = 0.5f * b0 + 0.5625f * b1 - 0.0625f * b2;
        }
        if (ty == 31 && og == 7) {
            float b0 = 0.f, b1 = 0.f, b2 = 0.f;
#pragma unroll
            for (int p = 0; p < 25; ++p) {
                b0 = fmaf(g[p], th[62 + p][oc], b0);
                b1 = fmaf(g[p], th[63 + p][oc], b1);
                b2 = fmaf(g[p], th[64 + p][oc], b2);
            }
            av[3] = -0.0625f * b0 + 0.5625f * b1 + 0.5f * b2;
        }
        float* dp = d1 + (size_t)c * MQ + (size_t)(32 * ty + 4 * og) * HALF + 32 * tx + oc;
#pragma unroll
        for (int k = 0; k < 4; ++k) dp[(size_t)k * HALF] = av[k];
    }
}

// ---- aK: d1 -> m1. main (17-tap composite, rows [16,2032)) + border blocks ----
__global__ __launch_bounds__(256) void aK(const float* __restrict__ d1,
                                          float* __restrict__ m1,
                                          const float* __restrict__ cf) {
    int b = blockIdx.x;
    int tid = threadIdx.x;
    if (b < 256 * NC) {
        int ib = b & 255, c = b >> 8;
        if (ib < 2 || ib > 253) return; // border blocks own those rows
        float C0[17], C1[17];
#pragma unroll
        for (int m = 0; m < 17; ++m) { C0[m] = cf[96 + m]; C1[m] = cf[128 + m]; }
        int i0 = 8 * ib, q0 = 4 * ib;
        const float* dp = d1 + ((size_t)c * MQ + (size_t)(q0 - 8) * HALF + 4 * tid);
        float4 acc[8];
#pragma unroll
        for (int k = 0; k < 8; ++k) acc[k] = make_float4(0.f, 0.f, 0.f, 0.f);
#pragma unroll
        for (int d = 0; d < 20; ++d) {
            float4 v = *(const float4*)(dp + (size_t)d * HALF);
#pragma unroll
            for (int k = 0; k < 8; ++k) {
                int m = d - (k >> 1);
                if (m >= 0 && m < 17) {
                    float wgt = (k & 1) ? C1[m] : C0[m];
                    acc[k].x = fmaf(wgt, v.x, acc[k].x);
                    acc[k].y = fmaf(wgt, v.y, acc[k].y);
                    acc[k].z = fmaf(wgt, v.z, acc[k].z);
                    acc[k].w = fmaf(wgt, v.w, acc[k].w);
                }
            }
        }
        float* mp = m1 + (size_t)c * M2 + (size_t)i0 * HALF + 4 * tid;
#pragma unroll
        for (int k = 0; k < 8; ++k) *(float4*)(mp + (size_t)k * HALF) = acc[k];
    } else {
        int bid = b - 256 * NC;
        int ri = bid & 31, c = bid >> 5;
        int i = ri < 16 ? ri : 2016 + ri;
        float g[25], hw[26];
#pragma unroll
        for (int p = 0; p < 25; ++p) g[p] = cf[p];
#pragma unroll
        for (int t = 0; t < 26; ++t) hw[t] = cf[32 + t];
        const float WE4[4] = {-0.0234375f, 0.2265625f, 0.8671875f, -0.0703125f};
        bool cl = (i == 2047);
        const float* db = d1 + (size_t)c * MQ + 4 * tid;
        float4 a = make_float4(0.f, 0.f, 0.f, 0.f);
#pragma unroll
        for (int t = 0; t < 26; ++t) {
            float wgt = cl ? (t < 25 ? g[t] : 0.f) : hw[t];
            int ip = (i - 12 + t) & 2047;
            int e = ip & 1, qq = (ip >> 1) + e - 2;
            float4 uv = make_float4(0.f, 0.f, 0.f, 0.f);
#pragma unroll
            for (int bq = 0; bq < 4; ++bq) {
                float wu = e ? WE4[3 - bq] : WE4[bq];
                int rr = refl(qq + bq, HALF);
                float4 v = *(const float4*)(db + (size_t)rr * HALF);
                uv.x = fmaf(wu, v.x, uv.x);
                uv.y = fmaf(wu, v.y, uv.y);
                uv.z = fmaf(wu, v.z, uv.z);
                uv.w = fmaf(wu, v.w, uv.w);
            }
            a.x = fmaf(wgt, uv.x, a.x);
            a.y = fmaf(wgt, uv.y, a.y);
            a.z = fmaf(wgt, uv.z, a.z);
            a.w = fmaf(wgt, uv.w, a.w);
        }
        *(float4*)(m1 + (size_t)c * M2 + (size_t)i * HALF + 4 * tid) = a;
    }
}

// ---- bK: m1,hx -> out. main (h composite + LAM*up(hx)) + border-col blocks ----
__global__ __launch_bounds__(256) void bK(const float* __restrict__ m1,
                                          const float* __restrict__ hx,
                                          float* __restrict__ out,
                                          const float* __restrict__ cf) {
    __shared__ float mr[4][1040];
    __shared__ float hv[4][1040];
    int b = blockIdx.x;
    int tid = threadIdx.x;
    const float WE4[4] = {-0.0234375f, 0.2265625f, 0.8671875f, -0.0703125f};
    if (b < 512 * NC) {
        int rb = b & 511, c = b >> 9;
        float C0[17], C1[17];
#pragma unroll
        for (int m = 0; m < 17; ++m) { C0[m] = cf[96 + m]; C1[m] = cf[128 + m]; }
        int i0 = 4 * rb;
        const float* mb = m1 + (size_t)c * M2 + (size_t)i0 * HALF;
#pragma unroll
        for (int r = 0; r < 4; ++r) {
            float4 v = *(const float4*)(mb + (size_t)r * HALF + 4 * tid);
            *(float4*)&mr[r][8 + 4 * tid] = v;
        }
        const float* hb = hx + (size_t)c * MQ;
        int q2 = 2 * rb;
#pragma unroll
        for (int k = 0; k < 4; ++k) {
            float4 a = make_float4(0.f, 0.f, 0.f, 0.f);
#pragma unroll
            for (int aq = 0; aq < 4; ++aq) {
                float wu = (k & 1) ? WE4[3 - aq] : WE4[aq];
                int row = refl(q2 - 2 + (k >> 1) + (k & 1) + aq, HALF);
                float4 v = *(const float4*)(hb + (size_t)row * HALF + 4 * tid);
                a.x = fmaf(wu, v.x, a.x);
                a.y = fmaf(wu, v.y, a.y);
                a.z = fmaf(wu, v.z, a.z);
                a.w = fmaf(wu, v.w, a.w);
            }
            *(float4*)&hv[k][4 + 4 * tid] = a;
            if (tid == 0) { hv[k][3] = a.x; hv[k][2] = a.y; }
            if (tid == 255) { hv[k][4 + 1024] = a.w; hv[k][4 + 1025] = a.z; }
        }
        __syncthreads();
        bool dostore = (tid >= 2 && tid <= 253); // border cols owned by border blocks
        float* ob = out + (size_t)c * HWSZ + (size_t)i0 * W + 8 * tid;
#pragma unroll
        for (int r = 0; r < 4; ++r) {
            float w[20];
#pragma unroll
            for (int q5 = 0; q5 < 5; ++q5)
                *(float4*)&w[4 * q5] = *(const float4*)&mr[r][4 * tid + 4 * q5];
            float wv[12];
#pragma unroll
            for (int q3 = 0; q3 < 3; ++q3)
                *(float4*)&wv[4 * q3] = *(const float4*)&hv[r][4 * tid + 4 * q3];
            float res[8];
#pragma unroll
            for (int s = 0; s < 8; ++s) {
                int h = s >> 1;
                float a = 0.f;
#pragma unroll
                for (int m = 0; m < 17; ++m)
                    a = fmaf((s & 1) ? C1[m] : C0[m], w[h + m], a);
                float uh = 0.f;
#pragma unroll
                for (int bq = 0; bq < 4; ++bq)
                    uh = fmaf((s & 1) ? WE4[3 - bq] : WE4[bq], wv[h + (s & 1) + 2 + bq], uh);
                res[s] = fmaf(LAM, uh, a);
            }
            if (dostore) {
                *(float4*)(ob + (size_t)r * W) = make_float4(res[0], res[1], res[2], res[3]);
                *(float4*)(ob + (size_t)r * W + 4) = make_float4(res[4], res[5], res[6], res[7]);
            }
        }
    } else {
        int bid = b - 512 * NC;
        int rg = bid & 255, c = bid >> 8;
        int i = 8 * rg + (tid >> 5);
        int cc = tid & 31;
        int j = cc < 16 ? cc : 2016 + cc;
        float g[25], hw[26];
#pragma unroll
        for (int p = 0; p < 25; ++p) g[p] = cf[p];
#pragma unroll
        for (int t = 0; t < 26; ++t) hw[t] = cf[32 + t];
        const float* mrow = m1 + (size_t)c * M2 + (size_t)i * HALF;
        bool cl = (j == 2047);
        float val = 0.f;
#pragma unroll
        for (int t = 0; t < 26; ++t) {
            float wgt = cl ? (t < 25 ? g[t] : 0.f) : hw[t];
            int jp = (j - 12 + t) & 2047;
            int e = jp & 1;
            int qq = (jp >> 1) + e - 2;
            float uh = 0.f;
#pragma unroll
            for (int bq = 0; bq < 4; ++bq)
                uh = fmaf(e ? WE4[3 - bq] : WE4[bq], mrow[refl(qq + bq, HALF)], uh);
            val = fmaf(wgt, uh, val);
        }
        const float* hb = hx + (size_t)c * MQ;
        int qi = (i >> 1) + (i & 1) - 2;
        int qj = (j >> 1) + (j & 1) - 2;
        float hval = 0.f;
#pragma unroll
        for (int aq = 0; aq < 4; ++aq) {
            const float* hr = hb + (size_t)refl(qi + aq, HALF) * HALF;
            float rowa = (i & 1) ? WE4[3 - aq] : WE4[aq];
            float s = 0.f;
#pragma unroll
            for (int bq = 0; bq < 4; ++bq)
                s = fmaf((j & 1) ? WE4[3 - bq] : WE4[bq], hr[refl(qj + bq, HALF)], s);
            hval = fmaf(rowa, s, hval);
        }
        out[(size_t)c * HWSZ + (size_t)i * W + j] = fmaf(LAM, hval, val);
    }
}

} // namespace

extern "C" void kernel_launch(void* const* d_in, const int* in_sizes, int n_in,
                              void* d_out, int out_size, void* d_ws, size_t ws_size,
                              hipStream_t stream) {
    (void)in_sizes; (void)n_in; (void)out_size; (void)ws_size;
    const float* x = (const float*)d_in[0];
    const float* k = (const float*)d_in[1];
    float* ws = (float*)d_ws;
    float* out = (float*)d_out;

    float* hxp = ws;            // 3*MQ
    float* d1 = hxp + 3 * MQ;   // 3*MQ
    float* m1 = d1 + 3 * MQ;    // 3*M2
    float* cf = m1 + 3 * M2;    // 160 floats

    hipLaunchKernelGGL(prep, dim3(1), dim3(32), 0, stream, k, cf);
    hipLaunchKernelGGL(front, dim3(32 * 32 * NC), dim3(256), 0, stream, x, d1, hxp, cf);
    hipLaunchKernelGGL(aK, dim3(256 * NC + 32 * NC), dim3(256), 0, stream, d1, m1, cf);
    hipLaunchKernelGGL(bK, dim3(512 * NC + 256 * NC), dim3(256), 0, stream, m1, hxp, out, cf);
}